// Round 4
// baseline (2916.698 us; speedup 1.0000x reference)
//
#include <hip/hip_runtime.h>
#include <stdint.h>

#define N_NODES 50000
#define N_GRAPHS 64
#define VOCAB 100000
#define DIM 256
#define N_EDGES 800000
#define T_SEQ 16
#define CAP 64          // max in-degree bucket capacity (Poisson(16) -> max deg ~40)

// Persistent-kernel geometry: 1536 blocks = 6 blocks/CU on 256 CUs.
// __launch_bounds__(256, 8) forces VGPR<=64 -> capacity is 8 blocks/CU, so
// co-residency (needed for the grid barrier) has 25% margin.
#define NBLK 1536

// phase vblock counts
#define VB_P0 260                 // 196 zero-counts + 64 zero-out
#define VB_FILL 3125              // N_EDGES/256 exactly
#define VB_CAST 12500
#define VB_TRAN 128
#define VB_P1 (VB_FILL + VB_CAST + VB_TRAN)
#define VB_ENC 12500
#define VB_GEMM 3128              // 782 m-tiles * 4 n-tiles (64x64 tiles)
#define VB_AGG 12500

typedef short bf16x8 __attribute__((ext_vector_type(8)));
typedef unsigned short u16x8 __attribute__((ext_vector_type(8)));
typedef unsigned short u16x4 __attribute__((ext_vector_type(4)));
typedef float f32x4 __attribute__((ext_vector_type(4)));
typedef unsigned short u16;

__device__ __forceinline__ float bf2f(u16 u) {
    union { unsigned int i; float f; } v; v.i = ((unsigned int)u) << 16; return v.f;
}
__device__ __forceinline__ u16 f2bf(float f) {
    union { float f; unsigned int i; } v; v.f = f;
    unsigned int x = v.i;
    return (u16)((x + 0x7fffu + ((x >> 16) & 1u)) >> 16);  // RNE, finite inputs
}

// ---- grid barrier (generation-based; agent-scope atomics + threadfence) ----
// cnt returns to 0 after every barrier, gen increases monotonically -> safe
// across graph replays without re-init (we still memset it for first-run
// safety). All NBLK blocks are co-resident by construction.
struct GridBar { int cnt; int gen; };

__device__ __forceinline__ void grid_bar(GridBar* b) {
    __syncthreads();
    if (threadIdx.x == 0) {
        __threadfence();   // release: push this block's stores device-wide
        int g = __hip_atomic_load(&b->gen, __ATOMIC_RELAXED, __HIP_MEMORY_SCOPE_AGENT);
        int a = __hip_atomic_fetch_add(&b->cnt, 1, __ATOMIC_ACQ_REL, __HIP_MEMORY_SCOPE_AGENT);
        if (a == NBLK - 1) {
            __hip_atomic_store(&b->cnt, 0, __ATOMIC_RELAXED, __HIP_MEMORY_SCOPE_AGENT);
            __hip_atomic_store(&b->gen, g + 1, __ATOMIC_RELEASE, __HIP_MEMORY_SCOPE_AGENT);
        } else {
            while (__hip_atomic_load(&b->gen, __ATOMIC_ACQUIRE, __HIP_MEMORY_SCOPE_AGENT) == g)
                __builtin_amdgcn_s_sleep(2);
        }
    }
    __syncthreads();
}

// ---- GEMM phase: C[M,256] = ((A @ W) + bias) * rsqrt(counts[row]+1) ----
// 64x64 block tile, 4 waves at 32x32 each -> acc 16 VGPR + frags 16, fits the
// 64-VGPR budget the persistent kernel needs. LDS 8KB (A 4K + B 4K).
__device__ __forceinline__ void gemm_phase(const u16* __restrict__ A,
        const u16* __restrict__ WT, const float* __restrict__ bias,
        const int* __restrict__ counts, u16* __restrict__ C,
        uint8_t* smem) {
    uint8_t* ldsA = smem;
    uint8_t* ldsB = smem + 4096;
    const int tid = threadIdx.x;
    const int wave = tid >> 6, lane = tid & 63;
    const int quad = lane >> 4, l16 = lane & 15;
    const int wm = wave & 1, wn = wave >> 1;
    const int srow = tid >> 2;              // 0..63 staging row
    const int scoff = (tid & 3) * 16;       // 16B chunk within 64B row

    for (int vb = blockIdx.x; vb < VB_GEMM; vb += NBLK) {
        int bm = (vb >> 2) * 64, bn = (vb & 3) * 64;
        int gr = bm + srow; if (gr > N_NODES - 1) gr = N_NODES - 1;
        const uint8_t* Asrc = (const uint8_t*)A + (size_t)gr * (DIM * 2) + scoff;
        const uint8_t* Bsrc = (const uint8_t*)WT + (size_t)(bn + srow) * (DIM * 2) + scoff;

        f32x4 acc[2][2] = {};
        for (int kt = 0; kt < 8; ++kt) {
            __syncthreads();
            *(uint4*)(ldsA + srow * 64 + scoff) = *(const uint4*)(Asrc + kt * 64);
            *(uint4*)(ldsB + srow * 64 + scoff) = *(const uint4*)(Bsrc + kt * 64);
            __syncthreads();
            bf16x8 afr[2], bfr[2];
#pragma unroll
            for (int t = 0; t < 2; ++t) {
                afr[t] = *(const bf16x8*)(ldsA + (wm * 32 + t * 16 + l16) * 64 + quad * 16);
                bfr[t] = *(const bf16x8*)(ldsB + (wn * 32 + t * 16 + l16) * 64 + quad * 16);
            }
#pragma unroll
            for (int tm = 0; tm < 2; ++tm)
#pragma unroll
                for (int tn = 0; tn < 2; ++tn)
                    acc[tm][tn] = __builtin_amdgcn_mfma_f32_16x16x32_bf16(
                        afr[tm], bfr[tn], acc[tm][tn], 0, 0, 0);
        }

        float bv[2];
#pragma unroll
        for (int tn = 0; tn < 2; ++tn) bv[tn] = bias[bn + wn * 32 + tn * 16 + l16];
#pragma unroll
        for (int tm = 0; tm < 2; ++tm) {
            int row0 = bm + wm * 32 + tm * 16 + quad * 4;
#pragma unroll
            for (int r = 0; r < 4; ++r) {
                int row = row0 + r;
                if (row < N_NODES) {
                    int cnt = counts[row]; if (cnt > CAP) cnt = CAP;
                    float dsc = rsqrtf((float)cnt + 1.0f);
#pragma unroll
                    for (int tn = 0; tn < 2; ++tn) {
                        int col = bn + wn * 32 + tn * 16 + l16;
                        C[(size_t)row * DIM + col] = f2bf((acc[tm][tn][r] + bv[tn]) * dsc);
                    }
                }
            }
        }
        __syncthreads();
    }
}

// ---- agg phase: z[n] = relu(rsqrt(cnt+1)*(sum_s h[s] + h[n])), h pre-scaled
__device__ __forceinline__ void agg_phase(const u16* __restrict__ h,
        const int* __restrict__ counts, const int* __restrict__ bucket,
        u16* __restrict__ z) {
    const int wave = threadIdx.x >> 6, lane = threadIdx.x & 63;
    const int half = lane >> 5, l32 = lane & 31;
    const int c = l32 * 8;
    for (int vb = blockIdx.x; vb < VB_AGG; vb += NBLK) {
        int n = vb * 4 + wave;              // < 50000 always
        float a[8];
        if (half == 0) {
            u16x8 v = *(const u16x8*)(h + (size_t)n * DIM + c);
#pragma unroll
            for (int j = 0; j < 8; ++j) a[j] = bf2f(v[j]);
        } else {
#pragma unroll
            for (int j = 0; j < 8; ++j) a[j] = 0.f;
        }
        int cnt = counts[n]; if (cnt > CAP) cnt = CAP;
        const int* bk = bucket + (size_t)n * CAP;
        int e = half;
        for (; e + 14 < cnt; e += 16) {
            int s0 = bk[e];      int s1 = bk[e + 2];
            int s2 = bk[e + 4];  int s3 = bk[e + 6];
            int s4 = bk[e + 8];  int s5 = bk[e + 10];
            int s6 = bk[e + 12]; int s7 = bk[e + 14];
            u16x8 v0 = *(const u16x8*)(h + (size_t)s0 * DIM + c);
            u16x8 v1 = *(const u16x8*)(h + (size_t)s1 * DIM + c);
            u16x8 v2 = *(const u16x8*)(h + (size_t)s2 * DIM + c);
            u16x8 v3 = *(const u16x8*)(h + (size_t)s3 * DIM + c);
            u16x8 v4 = *(const u16x8*)(h + (size_t)s4 * DIM + c);
            u16x8 v5 = *(const u16x8*)(h + (size_t)s5 * DIM + c);
            u16x8 v6 = *(const u16x8*)(h + (size_t)s6 * DIM + c);
            u16x8 v7 = *(const u16x8*)(h + (size_t)s7 * DIM + c);
            __builtin_amdgcn_sched_barrier(0);
#pragma unroll
            for (int j = 0; j < 8; ++j)
                a[j] += ((bf2f(v0[j]) + bf2f(v1[j])) + (bf2f(v2[j]) + bf2f(v3[j]))) +
                        ((bf2f(v4[j]) + bf2f(v5[j])) + (bf2f(v6[j]) + bf2f(v7[j])));
        }
        for (; e + 6 < cnt; e += 8) {
            int s0 = bk[e];     int s1 = bk[e + 2];
            int s2 = bk[e + 4]; int s3 = bk[e + 6];
            u16x8 v0 = *(const u16x8*)(h + (size_t)s0 * DIM + c);
            u16x8 v1 = *(const u16x8*)(h + (size_t)s1 * DIM + c);
            u16x8 v2 = *(const u16x8*)(h + (size_t)s2 * DIM + c);
            u16x8 v3 = *(const u16x8*)(h + (size_t)s3 * DIM + c);
#pragma unroll
            for (int j = 0; j < 8; ++j)
                a[j] += bf2f(v0[j]) + bf2f(v1[j]) + bf2f(v2[j]) + bf2f(v3[j]);
        }
        for (; e < cnt; e += 2) {
            int s = bk[e];
            u16x8 v = *(const u16x8*)(h + (size_t)s * DIM + c);
#pragma unroll
            for (int j = 0; j < 8; ++j) a[j] += bf2f(v[j]);
        }
#pragma unroll
        for (int j = 0; j < 8; ++j) a[j] += __shfl_xor(a[j], 32, 64);
        if (half == 0) {
            float dn = rsqrtf((float)cnt + 1.0f);
            u16x8 o;
#pragma unroll
            for (int j = 0; j < 8; ++j) o[j] = f2bf(fmaxf(a[j] * dn, 0.f));
            *(u16x8*)(z + (size_t)n * DIM + c) = o;
        }
    }
}

// ---- the whole pipeline as ONE persistent kernel, 8 phases, 7 grid barriers
__global__ __launch_bounds__(256, 8) void mega_kernel(
        const int* __restrict__ seq, const int* __restrict__ esrc,
        const int* __restrict__ edst, const int* __restrict__ batch,
        const float* __restrict__ emb, const float* __restrict__ W0,
        const float* __restrict__ b0, const float* __restrict__ W1,
        const float* __restrict__ b1,
        u16* __restrict__ emb_bf, u16* __restrict__ buf0, u16* __restrict__ buf1,
        int* __restrict__ bucket, int* __restrict__ counts,
        u16* __restrict__ WT0, u16* __restrict__ WT1,
        float* __restrict__ out, GridBar* bar) {
    __shared__ __align__(16) uint8_t smem[8448];
    const int tid = threadIdx.x;

    // ---- P0: zero counts + out (tiny) ----
    for (int vb = blockIdx.x; vb < VB_P0; vb += NBLK) {
        if (vb < 196) {
            int i = vb * 256 + tid;
            if (i < N_NODES) counts[i] = 0;
        } else {
            out[(vb - 196) * 256 + tid] = 0.f;
        }
    }
    grid_bar(bar);

    // ---- P1: fill (scatter, vb first so it starts immediately) + emb cast
    //          (stream) + W transpose. R3 lesson: never co-run fill with the
    //          gather phase; stream+scatter mix acceptably. ----
    for (int vb = blockIdx.x; vb < VB_P1; vb += NBLK) {
        if (vb < VB_FILL) {
            int e = vb * 256 + tid;         // 3125*256 == 800000 exactly
            int d = edst[e];
            int p = atomicAdd(&counts[d], 1);
            if (p < CAP) bucket[(size_t)d * CAP + p] = esrc[e];
        } else if (vb < VB_FILL + VB_CAST) {
            size_t base = ((size_t)(vb - VB_FILL) * 256 + tid) * 8;
            float4 a = *(const float4*)(emb + base);
            float4 b = *(const float4*)(emb + base + 4);
            ushort4 o0, o1;
            o0.x = f2bf(a.x); o0.y = f2bf(a.y); o0.z = f2bf(a.z); o0.w = f2bf(a.w);
            o1.x = f2bf(b.x); o1.y = f2bf(b.y); o1.z = f2bf(b.z); o1.w = f2bf(b.w);
            *(ushort4*)(emb_bf + base) = o0;
            *(ushort4*)(emb_bf + base + 4) = o1;
        } else {
            u16 (*tile)[33] = (u16(*)[33])smem;
            int b = vb - (VB_FILL + VB_CAST);
            int which = b >> 6;
            const float* W = which ? W1 : W0;
            u16* WT = which ? WT1 : WT0;
            b &= 63;
            int bx = b & 7, by = b >> 3;
            int tx = tid & 31, ty = tid >> 5;  // 32x8
            __syncthreads();
#pragma unroll
            for (int r = 0; r < 32; r += 8)
                tile[ty + r][tx] = f2bf(W[(size_t)(by * 32 + ty + r) * DIM + bx * 32 + tx]);
            __syncthreads();
#pragma unroll
            for (int r = 0; r < 32; r += 8)
                WT[(size_t)(bx * 32 + ty + r) * DIM + by * 32 + tx] = tile[tx][ty + r];
        }
    }
    grid_bar(bar);

    // ---- P2: encode — x[n,:] = sum_t emb_bf[seq[n,t],:] ----
    {
        const int wave = tid >> 6, lane = tid & 63;
        const int half = lane >> 5, l32 = lane & 31;
        const int c = l32 * 8;
        for (int vb = blockIdx.x; vb < VB_ENC; vb += NBLK) {
            int n = vb * 4 + wave;          // < 50000 always
            int toks[8];
#pragma unroll
            for (int tt = 0; tt < 8; ++tt)  // token t = half + 2*tt
                toks[tt] = seq[n * T_SEQ + half + 2 * tt];
            u16x8 v[8];
#pragma unroll
            for (int tt = 0; tt < 8; ++tt)
                v[tt] = *(const u16x8*)(emb_bf + (size_t)toks[tt] * DIM + c);
            __builtin_amdgcn_sched_barrier(0);
            float a[8] = {0.f, 0.f, 0.f, 0.f, 0.f, 0.f, 0.f, 0.f};
#pragma unroll
            for (int tt = 0; tt < 8; ++tt)
#pragma unroll
                for (int j = 0; j < 8; ++j) a[j] += bf2f(v[tt][j]);
#pragma unroll
            for (int j = 0; j < 8; ++j) a[j] += __shfl_xor(a[j], 32, 64);
            if (half == 0) {
                u16x8 o;
#pragma unroll
                for (int j = 0; j < 8; ++j) o[j] = f2bf(a[j]);
                *(u16x8*)(buf0 + (size_t)n * DIM + c) = o;
            }
        }
    }
    grid_bar(bar);

    // ---- P3: gemm0 ----
    gemm_phase(buf0, WT0, b0, counts, buf1, smem);
    grid_bar(bar);

    // ---- P4: agg0 ----
    agg_phase(buf1, counts, bucket, buf0);
    grid_bar(bar);

    // ---- P5: gemm1 ----
    gemm_phase(buf0, WT1, b1, counts, buf1, smem);
    grid_bar(bar);

    // ---- P6: agg1 ----
    agg_phase(buf1, counts, bucket, buf0);
    grid_bar(bar);

    // ---- P7: pool — out[g,:] += sum of buf0 rows with batch==g (sorted) ----
    {
        const int TW = NBLK * 4;                    // total waves
        const int NPW = (N_NODES + TW - 1) / TW;    // nodes per wave
        int gw = blockIdx.x * 4 + (tid >> 6);
        int lane = tid & 63;
        int n0 = gw * NPW;
        if (n0 < N_NODES) {
            int n1 = n0 + NPW; if (n1 > N_NODES) n1 = N_NODES;
            int c = lane * 4;
            float a0 = 0.f, a1 = 0.f, a2 = 0.f, a3 = 0.f;
            int gprev = -1;
            for (int n = n0; n < n1; ++n) {
                int g = batch[n];
                if (g != gprev) {
                    if (gprev >= 0) {
                        float* o = out + (size_t)gprev * DIM + c;
                        atomicAdd(o + 0, a0); atomicAdd(o + 1, a1);
                        atomicAdd(o + 2, a2); atomicAdd(o + 3, a3);
                    }
                    a0 = a1 = a2 = a3 = 0.f; gprev = g;
                }
                u16x4 v = *(const u16x4*)(buf0 + (size_t)n * DIM + c);
                a0 += bf2f(v[0]); a1 += bf2f(v[1]); a2 += bf2f(v[2]); a3 += bf2f(v[3]);
            }
            if (gprev >= 0) {
                float* o = out + (size_t)gprev * DIM + c;
                atomicAdd(o + 0, a0); atomicAdd(o + 1, a1);
                atomicAdd(o + 2, a2); atomicAdd(o + 3, a3);
            }
        }
    }
}

extern "C" void kernel_launch(void* const* d_in, const int* in_sizes, int n_in,
                              void* d_out, int out_size, void* d_ws, size_t ws_size,
                              hipStream_t stream) {
    const int*   seq   = (const int*)d_in[0];
    const int*   eidx  = (const int*)d_in[1];
    const int*   batch = (const int*)d_in[2];
    const float* emb   = (const float*)d_in[3];
    const float* W0    = (const float*)d_in[4];
    const float* b0    = (const float*)d_in[5];
    const float* W1    = (const float*)d_in[6];
    const float* b1    = (const float*)d_in[7];
    float* out = (float*)d_out;

    uint8_t* ws = (uint8_t*)d_ws;
    size_t off = 0;
    auto alloc = [&](size_t bytes) -> uint8_t* {
        uint8_t* p = ws + off;
        off += (bytes + 255) & ~(size_t)255;
        return p;
    };
    u16* emb_bf  = (u16*)alloc((size_t)VOCAB * DIM * 2);     // 51.2 MB
    u16* buf0    = (u16*)alloc((size_t)N_NODES * DIM * 2);   // 25.6 MB
    u16* buf1    = (u16*)alloc((size_t)N_NODES * DIM * 2);   // 25.6 MB
    int* bucket  = (int*)alloc((size_t)N_NODES * CAP * 4);   // 12.8 MB
    int* counts  = (int*)alloc((size_t)N_NODES * 4);
    u16* WT0     = (u16*)alloc((size_t)DIM * DIM * 2);
    u16* WT1     = (u16*)alloc((size_t)DIM * DIM * 2);
    GridBar* bar = (GridBar*)alloc(sizeof(GridBar));

    const int* esrc = eidx;
    const int* edst = eidx + N_EDGES;

    // 1 memset + 1 persistent kernel (was 7 dispatches with ~13us gaps each)
    hipMemsetAsync(bar, 0, sizeof(GridBar), stream);
    mega_kernel<<<NBLK, 256, 0, stream>>>(
        seq, esrc, edst, batch, emb, W0, b0, W1, b1,
        emb_bf, buf0, buf1, bucket, counts, WT0, WT1, out, bar);
}

// Round 5
// 441.986 us; speedup vs baseline: 6.5991x; 6.5991x over previous
//
#include <hip/hip_runtime.h>
#include <stdint.h>

#define N_NODES 50000
#define N_GRAPHS 64
#define VOCAB 100000
#define DIM 256
#define N_EDGES 800000
#define T_SEQ 16
#define CAP 64   // max in-degree bucket capacity (Poisson(16) -> max deg ~40)

typedef short bf16x8 __attribute__((ext_vector_type(8)));
typedef unsigned short u16x8 __attribute__((ext_vector_type(8)));
typedef unsigned short u16x4 __attribute__((ext_vector_type(4)));
typedef float f32x4 __attribute__((ext_vector_type(4)));
typedef unsigned short u16;

__device__ __forceinline__ float bf2f(u16 u) {
    union { unsigned int i; float f; } v; v.i = ((unsigned int)u) << 16; return v.f;
}
__device__ __forceinline__ u16 f2bf(float f) {
    union { float f; unsigned int i; } v; v.f = f;
    unsigned int x = v.i;
    return (u16)((x + 0x7fffu + ((x >> 16) & 1u)) >> 16);  // RNE, finite inputs
}

// direct global->LDS DMA, 16B per lane. LDS dest = (wave-uniform) base + lane*16.
__device__ __forceinline__ void gload_lds16(const void* g, void* l) {
    __builtin_amdgcn_global_load_lds(
        (const __attribute__((address_space(1))) uint32_t*)g,
        (__attribute__((address_space(3))) uint32_t*)l, 16, 0, 0);
}

// ---- prep: cast emb f32->bf16, transpose+cast W0/W1, zero counts & out ----
__global__ __launch_bounds__(256) void prep_kernel(const float* __restrict__ emb,
        u16* __restrict__ emb_bf, const float* __restrict__ W0, u16* __restrict__ WT0,
        const float* __restrict__ W1, u16* __restrict__ WT1,
        int* __restrict__ counts, float* __restrict__ out) {
    int bid = blockIdx.x;
    if (bid < 12500) {
        size_t base = ((size_t)bid * 256 + threadIdx.x) * 8;
        float4 a = *(const float4*)(emb + base);
        float4 b = *(const float4*)(emb + base + 4);
        ushort4 o0, o1;
        o0.x = f2bf(a.x); o0.y = f2bf(a.y); o0.z = f2bf(a.z); o0.w = f2bf(a.w);
        o1.x = f2bf(b.x); o1.y = f2bf(b.y); o1.z = f2bf(b.z); o1.w = f2bf(b.w);
        *(ushort4*)(emb_bf + base) = o0;
        *(ushort4*)(emb_bf + base + 4) = o1;
        if (bid < 196) {
            int i = bid * 256 + threadIdx.x;
            if (i < N_NODES) counts[i] = 0;
        }
        if (bid < 64) out[bid * 256 + threadIdx.x] = 0.f;
    } else {
        __shared__ u16 tile[32][33];
        int b = bid - 12500;
        int which = b >> 6;
        const float* W = which ? W1 : W0;
        u16* WT = which ? WT1 : WT0;
        b &= 63;
        int bx = b & 7, by = b >> 3;
        int tx = threadIdx.x & 31, ty = threadIdx.x >> 5;  // 32x8
#pragma unroll
        for (int r = 0; r < 32; r += 8)
            tile[ty + r][tx] = f2bf(W[(size_t)(by * 32 + ty + r) * DIM + bx * 32 + tx]);
        __syncthreads();
#pragma unroll
        for (int r = 0; r < 32; r += 8)
            WT[(size_t)(bx * 32 + ty + r) * DIM + by * 32 + tx] = tile[tx][ty + r];
    }
}

// ---- bucket fill: bucket[d*CAP + p] = src (u16), p = atomicAdd(counts[d]) ----
// u16 node ids (N_NODES < 65536): halves the scattered write-back traffic.
// R3/R4 lesson: keep this its own dispatch — fusing with any gather phase thrashes.
__global__ void fill_kernel(const int* __restrict__ src, const int* __restrict__ dst,
        int* __restrict__ counts, u16* __restrict__ bucket) {
    int e = blockIdx.x * 256 + threadIdx.x;
    if (e < N_EDGES) {
        int d = dst[e];
        int p = atomicAdd(&counts[d], 1);
        if (p < CAP) bucket[(size_t)d * CAP + p] = (u16)src[e];
    }
}

// ---- encoder: x[n,:] = sum_t emb_bf[seq[n,t],:] ----
// At the random-gather beyond-L2 BW floor (~3.6 TB/s); do not restructure.
__global__ __launch_bounds__(256) void encode_kernel(const int* __restrict__ seq,
        const u16* __restrict__ emb, u16* __restrict__ x) {
    int wave = threadIdx.x >> 6, lane = threadIdx.x & 63;
    int n = blockIdx.x * 4 + wave;
    if (n >= N_NODES) return;
    int half = lane >> 5, l32 = lane & 31;
    int c = l32 * 8;
    int toks[8];
#pragma unroll
    for (int tt = 0; tt < 8; ++tt)           // token t = half + 2*tt
        toks[tt] = seq[n * T_SEQ + half + 2 * tt];
    u16x8 v[8];
#pragma unroll
    for (int tt = 0; tt < 8; ++tt)
        v[tt] = *(const u16x8*)(emb + (size_t)toks[tt] * DIM + c);
    __builtin_amdgcn_sched_barrier(0);
    float a[8] = {0.f, 0.f, 0.f, 0.f, 0.f, 0.f, 0.f, 0.f};
#pragma unroll
    for (int tt = 0; tt < 8; ++tt)
#pragma unroll
        for (int j = 0; j < 8; ++j) a[j] += bf2f(v[tt][j]);
#pragma unroll
    for (int j = 0; j < 8; ++j) a[j] += __shfl_xor(a[j], 32, 64);
    if (half == 0) {
        u16x8 o;
#pragma unroll
        for (int j = 0; j < 8; ++j) o[j] = f2bf(a[j]);
        *(u16x8*)(x + (size_t)n * DIM + c) = o;
    }
}

// ---- GEMM: C[M,256] = ((A @ W) + bias) * rsqrt(counts[row]+1)  (bf16, MFMA)
// R1's known-good 128x128 LDS structure, staging upgraded to global_load_lds
// width=16 (no VGPR round-trip, no staging addr VALU). Per wave per K-step:
// 4 DMA issues (A q0,q1; B q0,q1), each 64 lanes x 16B = 1KB = 16 rows x 64B.
// LDS-linear requirement: base + l*16 == (l>>2)*64 + (l&3)*16 (identity). ✓
__global__ __launch_bounds__(256) void gemm_kernel(const u16* __restrict__ A,
        const u16* __restrict__ WT, const float* __restrict__ bias,
        const int* __restrict__ counts, u16* __restrict__ C, int M) {
    __shared__ __align__(16) uint8_t ldsA[128 * 64];  // [128 rows][32 bf16] 8KB
    __shared__ __align__(16) uint8_t ldsB[128 * 64];  // [128 cols][32 bf16] 8KB
    int tid = threadIdx.x;
    int wave = tid >> 6, lane = tid & 63;
    int quad = lane >> 4, l16 = lane & 15;
    int wm = wave & 1, wn = wave >> 1;
    int bm = blockIdx.y * 128, bn = blockIdx.x * 128;

    // staging geometry (per wave): rows [32*wave, 32*wave+32) of each tile
    int srow = wave * 32 + (lane >> 2);          // + q*16
    int sbyte = (lane & 3) * 16;
    uint8_t* dstA = ldsA + wave * 2048;          // + q*1024, wave-uniform
    uint8_t* dstB = ldsB + wave * 2048;

    f32x4 acc[4][4] = {};

    for (int kt = 0; kt < 8; ++kt) {
        int k0b = kt * 64;                       // byte offset of K-chunk
#pragma unroll
        for (int q = 0; q < 2; ++q) {
            int gr = bm + srow + q * 16; if (gr > M - 1) gr = M - 1;
            gload_lds16((const uint8_t*)A + (size_t)gr * (DIM * 2) + k0b + sbyte,
                        dstA + q * 1024);
            int gbr = bn + srow + q * 16;        // < 256 always
            gload_lds16((const uint8_t*)WT + (size_t)gbr * (DIM * 2) + k0b + sbyte,
                        dstB + q * 1024);
        }
        __syncthreads();                         // drains vmcnt incl. lds-DMA
        bf16x8 afr[4], bfr[4];
#pragma unroll
        for (int t = 0; t < 4; ++t) {
            afr[t] = *(const bf16x8*)(ldsA + (wm * 64 + t * 16 + l16) * 64 + quad * 16);
            bfr[t] = *(const bf16x8*)(ldsB + (wn * 64 + t * 16 + l16) * 64 + quad * 16);
        }
#pragma unroll
        for (int tm = 0; tm < 4; ++tm)
#pragma unroll
            for (int tn = 0; tn < 4; ++tn)
                acc[tm][tn] = __builtin_amdgcn_mfma_f32_16x16x32_bf16(
                    afr[tm], bfr[tn], acc[tm][tn], 0, 0, 0);
        __syncthreads();
    }

    float bv[4];
#pragma unroll
    for (int tn = 0; tn < 4; ++tn) bv[tn] = bias[bn + wn * 64 + tn * 16 + l16];
#pragma unroll
    for (int tm = 0; tm < 4; ++tm) {
        int row0 = bm + wm * 64 + tm * 16 + quad * 4;
#pragma unroll
        for (int r = 0; r < 4; ++r) {
            int row = row0 + r;
            if (row < M) {
                int cnt = counts[row]; if (cnt > CAP) cnt = CAP;
                float dsc = rsqrtf((float)cnt + 1.0f);
#pragma unroll
                for (int tn = 0; tn < 4; ++tn) {
                    int col = bn + wn * 64 + tn * 16 + l16;
                    C[(size_t)row * DIM + col] = f2bf((acc[tm][tn][r] + bv[tn]) * dsc);
                }
            }
        }
    }
}

// ---- pull aggregation (h pre-scaled by dis): z[n] = relu(dn*(sum_s h[s] + h[n]))
__global__ __launch_bounds__(256) void agg_kernel(const u16* __restrict__ h,
        const int* __restrict__ counts, const u16* __restrict__ bucket,
        u16* __restrict__ z) {
    int wave = threadIdx.x >> 6, lane = threadIdx.x & 63;
    int n = blockIdx.x * 4 + wave;
    if (n >= N_NODES) return;
    int half = lane >> 5, l32 = lane & 31;
    int c = l32 * 8;
    float a[8];
    if (half == 0) {
        u16x8 v = *(const u16x8*)(h + (size_t)n * DIM + c);
#pragma unroll
        for (int j = 0; j < 8; ++j) a[j] = bf2f(v[j]);
    } else {
#pragma unroll
        for (int j = 0; j < 8; ++j) a[j] = 0.f;
    }
    int cnt = counts[n]; if (cnt > CAP) cnt = CAP;
    const u16* bk = bucket + (size_t)n * CAP;
    int e = half;
    for (; e + 14 < cnt; e += 16) {          // 8 rows per half per iteration
        int s0 = bk[e];      int s1 = bk[e + 2];
        int s2 = bk[e + 4];  int s3 = bk[e + 6];
        int s4 = bk[e + 8];  int s5 = bk[e + 10];
        int s6 = bk[e + 12]; int s7 = bk[e + 14];
        u16x8 v0 = *(const u16x8*)(h + (size_t)s0 * DIM + c);
        u16x8 v1 = *(const u16x8*)(h + (size_t)s1 * DIM + c);
        u16x8 v2 = *(const u16x8*)(h + (size_t)s2 * DIM + c);
        u16x8 v3 = *(const u16x8*)(h + (size_t)s3 * DIM + c);
        u16x8 v4 = *(const u16x8*)(h + (size_t)s4 * DIM + c);
        u16x8 v5 = *(const u16x8*)(h + (size_t)s5 * DIM + c);
        u16x8 v6 = *(const u16x8*)(h + (size_t)s6 * DIM + c);
        u16x8 v7 = *(const u16x8*)(h + (size_t)s7 * DIM + c);
        __builtin_amdgcn_sched_barrier(0);   // keep all 8 gathers in flight
#pragma unroll
        for (int j = 0; j < 8; ++j)
            a[j] += ((bf2f(v0[j]) + bf2f(v1[j])) + (bf2f(v2[j]) + bf2f(v3[j]))) +
                    ((bf2f(v4[j]) + bf2f(v5[j])) + (bf2f(v6[j]) + bf2f(v7[j])));
    }
    for (; e + 6 < cnt; e += 8) {
        int s0 = bk[e];
        int s1 = bk[e + 2];
        int s2 = bk[e + 4];
        int s3 = bk[e + 6];
        u16x8 v0 = *(const u16x8*)(h + (size_t)s0 * DIM + c);
        u16x8 v1 = *(const u16x8*)(h + (size_t)s1 * DIM + c);
        u16x8 v2 = *(const u16x8*)(h + (size_t)s2 * DIM + c);
        u16x8 v3 = *(const u16x8*)(h + (size_t)s3 * DIM + c);
#pragma unroll
        for (int j = 0; j < 8; ++j)
            a[j] += bf2f(v0[j]) + bf2f(v1[j]) + bf2f(v2[j]) + bf2f(v3[j]);
    }
    for (; e < cnt; e += 2) {
        int s = bk[e];
        u16x8 v = *(const u16x8*)(h + (size_t)s * DIM + c);
#pragma unroll
        for (int j = 0; j < 8; ++j) a[j] += bf2f(v[j]);
    }
#pragma unroll
    for (int j = 0; j < 8; ++j) a[j] += __shfl_xor(a[j], 32, 64);
    if (half == 0) {
        float dn = rsqrtf((float)cnt + 1.0f);
        u16x8 o;
#pragma unroll
        for (int j = 0; j < 8; ++j) o[j] = f2bf(fmaxf(a[j] * dn, 0.f));
        *(u16x8*)(z + (size_t)n * DIM + c) = o;
    }
}

// ---- pooling: out[g,:] += sum of z rows with batch==g (batch sorted) ----
__global__ __launch_bounds__(256) void pool_kernel(const u16* __restrict__ z,
        const int* __restrict__ batch, float* __restrict__ out) {
    const int NWAVES = 4096;
    const int NPW = (N_NODES + NWAVES - 1) / NWAVES;  // 13
    int gw = blockIdx.x * 4 + (threadIdx.x >> 6);
    int lane = threadIdx.x & 63;
    int n0 = gw * NPW;
    if (n0 >= N_NODES) return;
    int n1 = n0 + NPW; if (n1 > N_NODES) n1 = N_NODES;
    int c = lane * 4;
    float a0 = 0.f, a1 = 0.f, a2 = 0.f, a3 = 0.f;
    int gprev = -1;
    for (int n = n0; n < n1; ++n) {
        int g = batch[n];
        if (g != gprev) {
            if (gprev >= 0) {
                float* o = out + (size_t)gprev * DIM + c;
                atomicAdd(o + 0, a0); atomicAdd(o + 1, a1);
                atomicAdd(o + 2, a2); atomicAdd(o + 3, a3);
            }
            a0 = a1 = a2 = a3 = 0.f; gprev = g;
        }
        u16x4 v = *(const u16x4*)(z + (size_t)n * DIM + c);
        a0 += bf2f(v[0]); a1 += bf2f(v[1]); a2 += bf2f(v[2]); a3 += bf2f(v[3]);
    }
    if (gprev >= 0) {
        float* o = out + (size_t)gprev * DIM + c;
        atomicAdd(o + 0, a0); atomicAdd(o + 1, a1);
        atomicAdd(o + 2, a2); atomicAdd(o + 3, a3);
    }
}

extern "C" void kernel_launch(void* const* d_in, const int* in_sizes, int n_in,
                              void* d_out, int out_size, void* d_ws, size_t ws_size,
                              hipStream_t stream) {
    const int*   seq   = (const int*)d_in[0];
    const int*   eidx  = (const int*)d_in[1];
    const int*   batch = (const int*)d_in[2];
    const float* emb   = (const float*)d_in[3];
    const float* W0    = (const float*)d_in[4];
    const float* b0    = (const float*)d_in[5];
    const float* W1    = (const float*)d_in[6];
    const float* b1    = (const float*)d_in[7];
    float* out = (float*)d_out;

    uint8_t* ws = (uint8_t*)d_ws;
    size_t off = 0;
    auto alloc = [&](size_t bytes) -> uint8_t* {
        uint8_t* p = ws + off;
        off += (bytes + 255) & ~(size_t)255;
        return p;
    };
    u16* emb_bf  = (u16*)alloc((size_t)VOCAB * DIM * 2);     // 51.2 MB
    u16* buf0    = (u16*)alloc((size_t)N_NODES * DIM * 2);   // 25.6 MB
    u16* buf1    = (u16*)alloc((size_t)N_NODES * DIM * 2);   // 25.6 MB
    u16* bucket  = (u16*)alloc((size_t)N_NODES * CAP * 2);   // 6.4 MB
    int* counts  = (int*)alloc((size_t)N_NODES * 4);
    u16* WT0     = (u16*)alloc((size_t)DIM * DIM * 2);
    u16* WT1     = (u16*)alloc((size_t)DIM * DIM * 2);

    const int* esrc = eidx;
    const int* edst = eidx + N_EDGES;

    // 8 dispatches
    prep_kernel<<<12500 + 128, 256, 0, stream>>>(emb, emb_bf, W0, WT0, W1, WT1,
                                                 counts, out);
    fill_kernel<<<(N_EDGES + 255) / 256, 256, 0, stream>>>(esrc, edst, counts, bucket);
    encode_kernel<<<(N_NODES + 3) / 4, 256, 0, stream>>>(seq, emb_bf, buf0);

    dim3 ggrid(2, (N_NODES + 127) / 128);  // (2, 391)
    gemm_kernel<<<ggrid, 256, 0, stream>>>(buf0, WT0, b0, counts, buf1, N_NODES);
    agg_kernel<<<(N_NODES + 3) / 4, 256, 0, stream>>>(buf1, counts, bucket, buf0);
    gemm_kernel<<<ggrid, 256, 0, stream>>>(buf0, WT1, b1, counts, buf1, N_NODES);
    agg_kernel<<<(N_NODES + 3) / 4, 256, 0, stream>>>(buf1, counts, bucket, buf0);

    pool_kernel<<<1024, 256, 0, stream>>>(buf0, batch, out);
}